// Round 8
// baseline (626.554 us; speedup 1.0000x reference)
//
#include <hip/hip_runtime.h>
#include <math.h>

// GreedyRouter: softmax gating + top-8 + renormalize + histogram.
// Insight: renormalized top-k softmax == softmax over only the top-k logits
// (full-row denominator cancels), so we never compute the full softmax.
//
// R5: NO-LDS consume. R3's residual stall was the per-chunk LDS transpose
// round-trip (vmcnt -> ds_write -> lgkmcnt -> ds_read) -- 512 LDS ops/lane
// all on the critical path. The coalesced load mapping f=lane+64i already
// gives lane L, chunk c: rows (L>>2)+{0,16,32,48}, cols (L&3)*4+c*16+{0..3}.
// So each lane keeps FOUR sorted top-8 lists (one per row, 64-col quarter)
// and inserts straight from the load registers. End: lanes 4t..4t+3 merge
// their quarters via shfl_xor(1),(2) + bitonic CE-16 (strict (v desc, idx
// asc) total order == jax tie-break; network verified in R4). Keeps R3's
// rotated register double-buffer (counted vmcnt; stores never awaited).
// launch_bounds(256,4): cap VGPR at 128 = grid's natural 16 waves/CU
// (R4's mistake was forcing 8 -> VGPR 32 -> spills).

constexpr int NEXP   = 256;   // experts
constexpr int TOPK   = 8;
constexpr int TPB    = 256;   // 4 waves per block, 64 tokens per wave
constexpr int CHUNK  = 16;    // columns per pipeline step
constexpr int NCHUNK = NEXP / CHUNK;   // 16
constexpr int F4T    = 4;     // float4 loads per lane per chunk

// branch-free bubble insert of (xval,xidx) into sorted-8 (desc, idx asc)
#define INS1(VL, IDL, xval, xidx)                                           \
    {                                                                       \
        float xx = (xval); int xi = (xidx);                                 \
        _Pragma("unroll")                                                   \
        for (int k = 0; k < TOPK; ++k) {                                    \
            bool  gt = xx > VL[k];                                          \
            float tv = VL[k];                                               \
            int   ti = IDL[k];                                              \
            VL[k]  = gt ? xx : tv;                                          \
            IDL[k] = gt ? xi : ti;                                          \
            xx     = gt ? tv : xx;                                          \
            xi     = gt ? ti : xi;                                          \
        }                                                                   \
    }
#define INS4(VL, IDL, Q, CB)                                                \
    INS1(VL, IDL, (Q).x, (CB))     INS1(VL, IDL, (Q).y, (CB) + 1)           \
    INS1(VL, IDL, (Q).z, (CB) + 2) INS1(VL, IDL, (Q).w, (CB) + 3)

// compare-exchange on merge scratch (keep larger at I; idx asc tie-break)
#define CE(I, J)                                                            \
    {                                                                       \
        bool sw = (mv[J] > mv[I]) || ((mv[J] == mv[I]) && (mi[J] < mi[I])); \
        float tv = mv[I]; int ti = mi[I];                                   \
        mv[I] = sw ? mv[J] : mv[I];  mi[I] = sw ? mi[J] : mi[I];            \
        mv[J] = sw ? tv : mv[J];     mi[J] = sw ? ti : mi[J];               \
    }

// merge this lane's sorted-8 with partner lane^XORW's (both end identical)
#define MSTAGE(VL, IDL, XORW)                                               \
    {                                                                       \
        float pv[TOPK]; int pid[TOPK];                                      \
        _Pragma("unroll")                                                   \
        for (int k = 0; k < TOPK; ++k) {                                    \
            pv[k]  = __shfl_xor(VL[k],  XORW, 64);                          \
            pid[k] = __shfl_xor(IDL[k], XORW, 64);                          \
        }                                                                   \
        float mv[16]; int mi[16];                                           \
        _Pragma("unroll")                                                   \
        for (int k = 0; k < TOPK; ++k) {                                    \
            mv[k] = VL[k];          mi[k] = IDL[k];                         \
            mv[8 + k] = pv[7 - k];  mi[8 + k] = pid[7 - k];                 \
        }                                                                   \
        CE(0, 8) CE(1, 9) CE(2, 10) CE(3, 11)                               \
        CE(4, 12) CE(5, 13) CE(6, 14) CE(7, 15)                             \
        CE(0, 4) CE(1, 5) CE(2, 6) CE(3, 7)                                 \
        CE(0, 2) CE(1, 3) CE(4, 6) CE(5, 7)                                 \
        CE(0, 1) CE(2, 3) CE(4, 5) CE(6, 7)                                 \
        _Pragma("unroll")                                                   \
        for (int k = 0; k < TOPK; ++k) { VL[k] = mv[k]; IDL[k] = mi[k]; }   \
    }

__global__ __launch_bounds__(TPB, 4) void router_kernel(
    const float* __restrict__ logits,
    float* __restrict__ out_logits,
    float* __restrict__ out_w,
    float* __restrict__ out_id,
    float* __restrict__ counts)
{
    __shared__ int hist[NEXP];   // 1024 B; no data tile at all

    const int tid  = threadIdx.x;
    const int wave = tid >> 6;
    const int lane = tid & 63;
    const int q    = lane & 3;        // col-quarter within 4-lane group
    const int tokw0 = blockIdx.x * TPB + wave * 64;

    hist[tid] = 0;
    __syncthreads();   // hist zeroed before any wave's atomics

    // 4 per-lane sorted top-8 lists: list l covers row (lane>>2)+16l,
    // cols == q*4 + c*16 + {0..3} (its 64-col quarter).
    float v0[TOPK], v1[TOPK], v2[TOPK], v3[TOPK];
    int  id0[TOPK], id1[TOPK], id2[TOPK], id3[TOPK];
#pragma unroll
    for (int k = 0; k < TOPK; ++k) {
        v0[k] = v1[k] = v2[k] = v3[k] = -INFINITY;
        id0[k] = id1[k] = id2[k] = id3[k] = 0;
    }

    // Static addressing: f = lane + 64*i -> row (lane>>2)+16i, col-group q.
    // Wave-load = 16 rows x 64B segments per instr (coalesced).
    size_t gbase[F4T];
#pragma unroll
    for (int i = 0; i < F4T; ++i)
        gbase[i] = (size_t)(tokw0 + (lane >> 2) + 16 * i) * NEXP + q * 4;

    // Named rotated buffers (runtime-indexed arrays would go to scratch).
    float4 xA[F4T], xB[F4T];

    // One step: chunk C sits in XC (loads issued one step earlier => oldest
    // outstanding vmcnt entries; counted wait leaves stores + L(C+1) in
    // flight). Consume straight from registers -- no LDS, no lgkmcnt.
#define STEP(C, XC, XN)                                                     \
    {                                                                       \
        const int c_ = (C);                                                 \
        if (c_ + 1 < NCHUNK) {                                              \
            const int off = (c_ + 1) * CHUNK;                               \
            _Pragma("unroll")                                               \
            for (int i = 0; i < F4T; ++i)                                   \
                XN[i] = *(const float4*)(logits + gbase[i] + off);          \
        }                                                                   \
        {                                                                   \
            const int off = c_ * CHUNK;                                     \
            _Pragma("unroll")                                               \
            for (int i = 0; i < F4T; ++i)                                   \
                *(float4*)(out_logits + gbase[i] + off) = XC[i];            \
        }                                                                   \
        const int cb = c_ * CHUNK + q * 4;                                  \
        INS4(v0, id0, XC[0], cb)                                            \
        INS4(v1, id1, XC[1], cb)                                            \
        INS4(v2, id2, XC[2], cb)                                            \
        INS4(v3, id3, XC[3], cb)                                            \
    }

    // ---- prologue: issue chunk 0 loads into xA ----
#pragma unroll
    for (int i = 0; i < F4T; ++i)
        xA[i] = *(const float4*)(logits + gbase[i]);

    // ---- main pipeline: zero barriers, zero LDS, stores never awaited ----
#pragma unroll 1
    for (int c = 0; c < NCHUNK; c += 2) {
        STEP(c,     xA, xB);
        STEP(c + 1, xB, xA);
    }
#undef STEP

    // ---- per list: merge quarters across the 4-lane group, then output.
    // Processing one list fully at a time bounds peak register pressure.
#define FINISH(VL, IDL, LIDX)                                               \
    {                                                                       \
        MSTAGE(VL, IDL, 1)                                                  \
        MSTAGE(VL, IDL, 2)                                                  \
        /* all 4 lanes now hold the identical exact top-8 of this row */    \
        float e[TOPK]; float s = 0.f;                                       \
        _Pragma("unroll")                                                   \
        for (int k = 0; k < TOPK; ++k) {                                    \
            e[k] = __expf(VL[k] - VL[0]); s += e[k];                        \
        }                                                                   \
        const float inv = 1.0f / s;                                         \
        _Pragma("unroll")                                                   \
        for (int k = 0; k < TOPK; ++k) e[k] *= inv;                         \
        /* static cndmask selection: lane q writes elements 2q, 2q+1 */     \
        float wa = q == 0 ? e[0] : q == 1 ? e[2] : q == 2 ? e[4] : e[6];    \
        float wb = q == 0 ? e[1] : q == 1 ? e[3] : q == 2 ? e[5] : e[7];    \
        int   ia = q == 0 ? IDL[0] : q == 1 ? IDL[2]                        \
                          : q == 2 ? IDL[4] : IDL[6];                       \
        int   ib = q == 0 ? IDL[1] : q == 1 ? IDL[3]                        \
                          : q == 2 ? IDL[5] : IDL[7];                       \
        const size_t token = (size_t)(tokw0 + (lane >> 2) + 16 * (LIDX));   \
        *(float2*)(out_w  + token * TOPK + q * 2) =                         \
            make_float2(wa, wb);                                            \
        *(float2*)(out_id + token * TOPK + q * 2) =                         \
            make_float2((float)ia, (float)ib);                              \
        atomicAdd(&hist[ia], 1);                                            \
        atomicAdd(&hist[ib], 1);                                            \
    }

    FINISH(v0, id0, 0)
    FINISH(v1, id1, 1)
    FINISH(v2, id2, 2)
    FINISH(v3, id3, 3)
#undef FINISH

    __syncthreads();
    // one global atomic per (block, expert)
    atomicAdd(&counts[tid], (float)hist[tid]);
}

extern "C" void kernel_launch(void* const* d_in, const int* in_sizes, int n_in,
                              void* d_out, int out_size, void* d_ws, size_t ws_size,
                              hipStream_t stream) {
    const float* logits = (const float*)d_in[0];
    const int n_tokens  = in_sizes[0] / NEXP;

    float* out        = (float*)d_out;
    float* out_logits = out;
    float* out_w      = out_logits + (size_t)n_tokens * NEXP;
    float* out_id     = out_w      + (size_t)n_tokens * TOPK;
    float* counts     = out_id     + (size_t)n_tokens * TOPK;

    // d_out is re-poisoned to 0xAA before every launch; histogram needs zeros.
    hipMemsetAsync(counts, 0, NEXP * sizeof(float), stream);

    const int blocks = n_tokens / TPB;  // 262144/256 = 1024
    router_kernel<<<blocks, TPB, 0, stream>>>(logits, out_logits, out_w,
                                              out_id, counts);
}